// Round 6
// baseline (277.914 us; speedup 1.0000x reference)
//
#include <hip/hip_runtime.h>
#include <hip/hip_bf16.h>
#include <string.h>

// Problem constants
#define NB    4096      // batch rows
#define IND_  512       // feature dim
#define OUTD_ 512       // output dim (GEMM M, "o")
#define XCOLS 514       // P + IND
#define ND    25        // D^P
#define KTOT  12800     // IND_*ND
#define KT2   12864     // KTOT + 64 bias-tail tile

// GEMM tiling
#define BM 128
#define BN 128
#define BK 64

typedef float  f32x4  __attribute__((ext_vector_type(4)));
typedef __bf16 bf16x8 __attribute__((ext_vector_type(8)));
typedef unsigned short u16x8 __attribute__((ext_vector_type(8)));
typedef unsigned int   u32x4 __attribute__((ext_vector_type(4)));

__device__ __forceinline__ unsigned short f2bf(float f) {
  unsigned int x = __float_as_uint(f);
  return (unsigned short)((x + 0x7fffu + ((x >> 16) & 1u)) >> 16);
}

__device__ __forceinline__ float bf2f(unsigned short u) {
  return __uint_as_float(((unsigned int)u) << 16);
}

// HW packed cvt: v_cvt_pk_bf16_f32 (memcpy instead of bit_cast: __hip_bfloat162
// is not trivially copyable -> round-4 compile failure)
__device__ __forceinline__ unsigned int pk_bf16(float a, float b) {
  float2 f; f.x = a; f.y = b;
  __hip_bfloat162 h = __float22bfloat162_rn(f);
  unsigned int u;
  __builtin_memcpy(&u, &h, 4);
  return u;
}

__device__ __forceinline__ float basis_f(float t, int j) {
  switch (j) {
    case 0: return 1.0f;
    case 1: return t;
    case 2: return t * t;
    case 3: { float r = t - 0.33f; r = r > 0.0f ? r : 0.0f; return r * r; }
    default:{ float r = t - 0.66f; r = r > 0.0f ? r : 0.0f; return r * r; }
  }
}

__device__ __forceinline__ void gload_lds16(const void* g, void* l) {
  __builtin_amdgcn_global_load_lds(
      (const __attribute__((address_space(1))) void*)g,
      (__attribute__((address_space(3))) void*)l, 16, 0, 0);
}

// ---------------------------------------------------------------------------
// prep_x: per row b: kb[b][25], XFb[b][i] (bf16), out[b][0:2] = x_treat
// ---------------------------------------------------------------------------
__global__ __launch_bounds__(256) void prep_x_kernel(
    const float* __restrict__ x, unsigned short* __restrict__ XFb,
    float* __restrict__ kb, float* __restrict__ out)
{
  const int b    = blockIdx.x * 4 + (threadIdx.x >> 6);
  const int lane = threadIdx.x & 63;
  const float* xr = x + (size_t)b * XCOLS;

  const float* fp = xr + 2 + lane * 8;
  float2 a0 = *(const float2*)(fp + 0);
  float2 a1 = *(const float2*)(fp + 2);
  float2 a2 = *(const float2*)(fp + 4);
  float2 a3 = *(const float2*)(fp + 6);
  u16x8 pk;
  pk[0] = f2bf(a0.x); pk[1] = f2bf(a0.y); pk[2] = f2bf(a1.x); pk[3] = f2bf(a1.y);
  pk[4] = f2bf(a2.x); pk[5] = f2bf(a2.y); pk[6] = f2bf(a3.x); pk[7] = f2bf(a3.y);
  *reinterpret_cast<u16x8*>(XFb + (size_t)b * IND_ + lane * 8) = pk;

  float t0 = xr[0], t1 = xr[1];
  if (lane < 2) out[(size_t)b * XCOLS + lane] = (lane == 0) ? t0 : t1;
  if (lane < ND) {
    int d1 = lane / 5;
    int d2 = lane - d1 * 5;
    kb[(size_t)b * ND + lane] = basis_f(t0, d1) * basis_f(t1, d2);
  }
}

// ---------------------------------------------------------------------------
// prep_w: W[i,o,d] (fp32) -> Wt[o][d*512+i] (bf16, row stride KT2).
// Two LDS stages: coalesced global read AND coalesced global write.
// ---------------------------------------------------------------------------
#define PWI 32
#define PWO 8
#define PWC (PWO * ND)   // 200 columns (o_l*25 + d)
#define PWP 208          // padded float stride
#define OLS 36           // out_ls padded ushort stride

__global__ __launch_bounds__(256) void prep_w_kernel(
    const float* __restrict__ W, unsigned short* __restrict__ Wt)
{
  __shared__ float tile[PWI * PWP];            // 26.6 KB
  __shared__ unsigned short out_ls[PWC * OLS]; // 14.4 KB
  const int tid = threadIdx.x;
  const int i0  = blockIdx.x * PWI;
  const int o0  = blockIdx.y * PWO;

  for (int idx = tid; idx < PWI * (PWC / 4); idx += 256) {
    int il = idx / (PWC / 4);
    int c4 = idx - il * (PWC / 4);
    float4 v = *(const float4*)(W + ((size_t)(i0 + il) * OUTD_ + o0) * ND + c4 * 4);
    *(float4*)&tile[il * PWP + c4 * 4] = v;
  }
  __syncthreads();

  if (tid < PWC) {
    #pragma unroll
    for (int j = 0; j < PWI / 8; ++j) {
      u16x8 pk;
      #pragma unroll
      for (int jj = 0; jj < 8; ++jj)
        pk[jj] = f2bf(tile[(j * 8 + jj) * PWP + tid]);
      *reinterpret_cast<u16x8*>(&out_ls[tid * OLS + j * 8]) = pk;
    }
  }
  __syncthreads();

  for (int g = tid; g < PWC * (PWI / 8); g += 256) {
    int c  = g >> 2;
    int ig = g & 3;
    int d  = c % 25;
    int o_l = c / 25;
    u16x8 v = *reinterpret_cast<const u16x8*>(&out_ls[c * OLS + ig * 8]);
    size_t rowb = (size_t)(o0 + o_l) * KT2 + (size_t)d * IND_ + i0;
    *reinterpret_cast<u16x8*>(Wt + rowb + ig * 8) = v;
  }
}

// ---------------------------------------------------------------------------
// prep_tail: Wt[o][12800+t] = t<25 ? bf16(bias[o][t]) : 0   (bias K-tail)
// ---------------------------------------------------------------------------
__global__ __launch_bounds__(256) void prep_tail_kernel(
    const float* __restrict__ bias, unsigned short* __restrict__ Wt)
{
  const int idx = blockIdx.x * 256 + threadIdx.x;   // < 512*64
  const int o = idx >> 6;
  const int t = idx & 63;
  unsigned short v = (t < ND) ? f2bf(bias[o * ND + t]) : (unsigned short)0;
  Wt[(size_t)o * KT2 + KTOT + t] = v;
}

// ---------------------------------------------------------------------------
// gemm_fused2: C[o][b] = sum_k A[o][k] * B[b][k] over K=12864 where
//   A[o][k<12800] = Wt, A[o][12800+d] = bias[o][d]
//   B[b][k]       = kb[b,d(k)]*xf[b,i(k)],   B[b][12800+d] = kb[b,d]
// Split-K 4 (last split takes the bias tile).  ONE barrier per K-iter:
//   [issue A(n+1) async -> Als[q]; load B(n+1) -> regs]  (overlaps MFMA)
//   [32 MFMAs on Als[p]/Bls[p]]
//   [cvt+scale regs -> ds_write Bls[q]]
//   __syncthreads()
// LDS 64KB (2 blocks/CU).  Swizzled granules: conflict-free (round-3 proven).
// ---------------------------------------------------------------------------
__global__ void gemm_fused2_kernel(
    const unsigned short* __restrict__ Wt, const unsigned short* __restrict__ XFb,
    const float* __restrict__ kb, float* __restrict__ P)
{
  __shared__ unsigned short Als[2][BM * BK];   // 2 x 16 KB
  __shared__ unsigned short Bls[2][BN * BK];   // 2 x 16 KB

  const int tid  = threadIdx.x;
  const int lane = tid & 63;
  const int w    = tid >> 6;
  const int l15  = lane & 15;
  const int quad = lane >> 4;

  // round-3 proven XCD mapping: 512 blocks, id%8 = XCD
  const int id  = blockIdx.x;
  const int xcd = id & 7;
  const int j   = id >> 3;              // [0,64)
  const int bx  = j & 3;                // o-tile
  const int pg  = xcd * 16 + (j >> 2);  // [0,128): (b-tile, split)
  const int by  = pg & 31;
  const int bz  = pg >> 5;              // split [0,4)

  const int o0 = bx * BM;
  const int b0 = by * BN;
  const int ks_begin = bz * 3200;
  const int ks_end   = (bz == 3) ? KT2 : ks_begin + 3200;

  const int o_off = (w & 1) * 64;
  const int b_off = (w >> 1) * 64;
  const int srow  = lane >> 3;                 // 0..7 row-in-chunk
  const int sg    = lane & 7;                  // logical granule
  const int pgr   = sg ^ srow;                 // phys (swizzled) granule
  const int scol  = pgr * 8;                   // A: swizzled SOURCE col
  const int r7    = l15 & 7;

  f32x4 acc[4][4];
  #pragma unroll
  for (int i = 0; i < 4; ++i)
    #pragma unroll
    for (int jj = 0; jj < 4; ++jj) acc[i][jj] = (f32x4)0.0f;

  u16x8 vr[4];
  float sc[4];

  // ---- helpers as lambdas (inlined) ----
  auto issueA = [&](int k0, int buf) {
    #pragma unroll
    for (int c = 0; c < 4; ++c) {
      int chunk = w * 4 + c;
      int r = chunk * 8 + srow;
      gload_lds16(Wt + (size_t)(o0 + r) * KT2 + k0 + scol, &Als[buf][chunk * 512]);
    }
  };
  auto loadB = [&](int k0) {
    if (k0 < KTOT) {
      const int d  = k0 >> 9;
      const int i0 = k0 & 511;
      #pragma unroll
      for (int c = 0; c < 4; ++c) {
        int chunk = w * 4 + c;
        int row = chunk * 8 + srow;
        vr[c] = *(const u16x8*)(XFb + (size_t)(b0 + row) * IND_ + i0 + sg * 8);
        sc[c] = kb[(size_t)(b0 + row) * ND + d];
      }
    } else {
      // bias tail: B[b][12800+dd] = kb[b,dd] (dd<25) else 0
      #pragma unroll
      for (int c = 0; c < 4; ++c) {
        int chunk = w * 4 + c;
        int row = chunk * 8 + srow;
        u16x8 t;
        #pragma unroll
        for (int jj = 0; jj < 8; ++jj) {
          int dd = sg * 8 + jj;
          t[jj] = (dd < ND) ? f2bf(kb[(size_t)(b0 + row) * ND + dd]) : (unsigned short)0;
        }
        vr[c] = t;
        sc[c] = 1.0f;
      }
    }
  };
  auto writeB = [&](int buf) {
    #pragma unroll
    for (int c = 0; c < 4; ++c) {
      int chunk = w * 4 + c;
      int row = chunk * 8 + srow;
      u32x4 rp;
      #pragma unroll
      for (int p4 = 0; p4 < 4; ++p4)
        rp[p4] = pk_bf16(bf2f(vr[c][2 * p4]) * sc[c], bf2f(vr[c][2 * p4 + 1]) * sc[c]);
      *reinterpret_cast<u32x4*>(&Bls[buf][row * BK + pgr * 8]) = rp;
    }
  };

  // ---- prologue: stage iter 0 ----
  issueA(ks_begin, 0);
  loadB(ks_begin);
  writeB(0);
  __syncthreads();

  // ---- main loop: one barrier per iter ----
  int n = 0;
  for (int k0 = ks_begin; k0 < ks_end; k0 += BK, ++n) {
    const int p = n & 1;
    const int q = p ^ 1;
    const int k1 = k0 + BK;
    const bool more = (k1 < ks_end);

    if (more) {
      issueA(k1, q);      // async, lands in Als[q]; overlaps MFMA below
      loadB(k1);          // global->regs; overlaps MFMA below
    }

    #pragma unroll
    for (int ks = 0; ks < 2; ++ks) {
      bf16x8 af[4], bfr[4];
      #pragma unroll
      for (int mf = 0; mf < 4; ++mf) {
        int row = o_off + mf * 16 + l15;
        int g   = (ks * 4 + quad) ^ r7;
        af[mf] = *reinterpret_cast<const bf16x8*>(&Als[p][row * BK + g * 8]);
      }
      #pragma unroll
      for (int nf = 0; nf < 4; ++nf) {
        int row = b_off + nf * 16 + l15;
        int g   = (ks * 4 + quad) ^ r7;
        bfr[nf] = *reinterpret_cast<const bf16x8*>(&Bls[p][row * BK + g * 8]);
      }
      #pragma unroll
      for (int mf = 0; mf < 4; ++mf)
        #pragma unroll
        for (int nf = 0; nf < 4; ++nf)
          acc[mf][nf] = __builtin_amdgcn_mfma_f32_16x16x32_bf16(
              af[mf], bfr[nf], acc[mf][nf], 0, 0, 0);
    }

    if (more) writeB(q);
    __syncthreads();
  }

  float* Pz = P + (size_t)bz * NB * OUTD_;
  #pragma unroll
  for (int mf = 0; mf < 4; ++mf)
    #pragma unroll
    for (int nf = 0; nf < 4; ++nf) {
      int bg = b0 + b_off + nf * 16 + l15;
      int og = o0 + o_off + mf * 16 + quad * 4;
      *reinterpret_cast<f32x4*>(&Pz[(size_t)bg * OUTD_ + og]) = acc[mf][nf];
    }
}

// ---------------------------------------------------------------------------
// epilogue: out[b][2+o] = relu(P0+P1+P2+P3)   (bias already in GEMM K-tail)
// ---------------------------------------------------------------------------
__global__ __launch_bounds__(256) void epilogue_kernel(
    const float* __restrict__ P, float* __restrict__ out)
{
  const int idx = blockIdx.x * 256 + threadIdx.x;   // < 4096*512
  const int b = idx >> 9;
  const int o = idx & 511;
  const size_t stride = (size_t)NB * OUTD_;
  float s = P[idx] + P[stride + idx] + P[2 * stride + idx] + P[3 * stride + idx];
  out[(size_t)b * XCOLS + 2 + o] = s > 0.0f ? s : 0.0f;
}

// ---------------------------------------------------------------------------
extern "C" void kernel_launch(void* const* d_in, const int* in_sizes, int n_in,
                              void* d_out, int out_size, void* d_ws, size_t ws_size,
                              hipStream_t stream) {
  const float* x    = (const float*)d_in[0];   // 4096 x 514
  const float* W    = (const float*)d_in[1];   // 512 x 512 x 25
  const float* bias = (const float*)d_in[2];   // 512 x 25
  float* out = (float*)d_out;
  char* ws = (char*)d_ws;

  // ws layout (bytes):
  //   XFb 4,194,304 | Wt 512*12864*2 = 13,172,736 | kb 409,600 | P 33,554,432
  const size_t xfb_off = 0;
  const size_t wt_off  = 4194304;
  const size_t kb_off  = wt_off + (size_t)OUTD_ * KT2 * 2;   // 17,367,040
  const size_t p_off   = kb_off + 409600;                     // 17,776,640
  unsigned short* XFb = (unsigned short*)(ws + xfb_off);
  unsigned short* Wt  = (unsigned short*)(ws + wt_off);
  float* kb           = (float*)(ws + kb_off);
  float* P            = (float*)(ws + p_off);

  prep_x_kernel<<<NB / 4, 256, 0, stream>>>(x, XFb, kb, out);
  prep_w_kernel<<<dim3(IND_ / PWI, OUTD_ / PWO), 256, 0, stream>>>(W, Wt);
  prep_tail_kernel<<<(OUTD_ * 64) / 256, 256, 0, stream>>>(bias, Wt);
  gemm_fused2_kernel<<<512, 256, 0, stream>>>(Wt, XFb, kb, P);
  epilogue_kernel<<<(NB * OUTD_) / 256, 256, 0, stream>>>(P, out);
}

// Round 8
// 178.181 us; speedup vs baseline: 1.5597x; 1.5597x over previous
//
#include <hip/hip_runtime.h>
#include <hip/hip_bf16.h>
#include <string.h>

// Problem constants
#define NB    4096      // batch rows
#define IND_  512       // feature dim
#define OUTD_ 512       // output dim (GEMM M, "o")
#define XCOLS 514      // P + IND
#define ND    25        // D^P
#define KTOT  12800     // IND_*ND
#define KT2   12864     // KTOT + 64 bias-tail tile

// GEMM tiling
#define BM 128
#define BN 128
#define BK 64

typedef float  f32x4  __attribute__((ext_vector_type(4)));
typedef __bf16 bf16x8 __attribute__((ext_vector_type(8)));
typedef unsigned short u16x8 __attribute__((ext_vector_type(8)));
typedef unsigned int   u32x4 __attribute__((ext_vector_type(4)));

__device__ __forceinline__ unsigned short f2bf(float f) {
  unsigned int x = __float_as_uint(f);
  return (unsigned short)((x + 0x7fffu + ((x >> 16) & 1u)) >> 16);
}

__device__ __forceinline__ float bf2f(unsigned short u) {
  return __uint_as_float(((unsigned int)u) << 16);
}

// HW packed cvt (memcpy, NOT bit_cast: __hip_bfloat162 is not trivially
// copyable -> round-4 compile failure)
__device__ __forceinline__ unsigned int pk_bf16(float a, float b) {
  float2 f; f.x = a; f.y = b;
  __hip_bfloat162 h = __float22bfloat162_rn(f);
  unsigned int u;
  __builtin_memcpy(&u, &h, 4);
  return u;
}

__device__ __forceinline__ float basis_f(float t, int j) {
  switch (j) {
    case 0: return 1.0f;
    case 1: return t;
    case 2: return t * t;
    case 3: { float r = t - 0.33f; r = r > 0.0f ? r : 0.0f; return r * r; }
    default:{ float r = t - 0.66f; r = r > 0.0f ? r : 0.0f; return r * r; }
  }
}

__device__ __forceinline__ void gload_lds16(const void* g, void* l) {
  __builtin_amdgcn_global_load_lds(
      (const __attribute__((address_space(1))) void*)g,
      (__attribute__((address_space(3))) void*)l, 16, 0, 0);
}

// Explicit full drain. REQUIRED before each __syncthreads in the pipelined
// gemm: global_load_lds data is consumed by OTHER waves after the barrier,
// so each wave must drain its OWN vmcnt before s_barrier. With the prefetch
// hoisted above the MFMA block the compiler may tie the wait to the first
// self-use (after the barrier) instead -> rare cross-wave race (round 7:
// post-timing divergence absmax 1359).
__device__ __forceinline__ void drain_all() {
  asm volatile("s_waitcnt vmcnt(0) lgkmcnt(0)" ::: "memory");
}

// ---------------------------------------------------------------------------
// prep_x: per row b: kb[b][25], XFb[b][i] (bf16), out[b][0:2] = x_treat
// ---------------------------------------------------------------------------
__global__ __launch_bounds__(256) void prep_x_kernel(
    const float* __restrict__ x, unsigned short* __restrict__ XFb,
    float* __restrict__ kb, float* __restrict__ out)
{
  const int b    = blockIdx.x * 4 + (threadIdx.x >> 6);
  const int lane = threadIdx.x & 63;
  const float* xr = x + (size_t)b * XCOLS;

  const float* fp = xr + 2 + lane * 8;
  float2 a0 = *(const float2*)(fp + 0);
  float2 a1 = *(const float2*)(fp + 2);
  float2 a2 = *(const float2*)(fp + 4);
  float2 a3 = *(const float2*)(fp + 6);
  u16x8 pk;
  pk[0] = f2bf(a0.x); pk[1] = f2bf(a0.y); pk[2] = f2bf(a1.x); pk[3] = f2bf(a1.y);
  pk[4] = f2bf(a2.x); pk[5] = f2bf(a2.y); pk[6] = f2bf(a3.x); pk[7] = f2bf(a3.y);
  *reinterpret_cast<u16x8*>(XFb + (size_t)b * IND_ + lane * 8) = pk;

  float t0 = xr[0], t1 = xr[1];
  if (lane < 2) out[(size_t)b * XCOLS + lane] = (lane == 0) ? t0 : t1;
  if (lane < ND) {
    int d1 = lane / 5;
    int d2 = lane - d1 * 5;
    kb[(size_t)b * ND + lane] = basis_f(t0, d1) * basis_f(t1, d2);
  }
}

// ---------------------------------------------------------------------------
// prep_w: W[i,o,d] (fp32) -> Wt[o][d*512+i] (bf16, row stride KT2).
// Two LDS stages: coalesced global read AND coalesced global write.
// ---------------------------------------------------------------------------
#define PWI 32
#define PWO 8
#define PWC (PWO * ND)   // 200 columns (o_l*25 + d)
#define PWP 208          // padded float stride
#define OLS 36           // out_ls padded ushort stride

__global__ __launch_bounds__(256) void prep_w_kernel(
    const float* __restrict__ W, unsigned short* __restrict__ Wt)
{
  __shared__ float tile[PWI * PWP];            // 26.6 KB
  __shared__ unsigned short out_ls[PWC * OLS]; // 14.4 KB
  const int tid = threadIdx.x;
  const int i0  = blockIdx.x * PWI;
  const int o0  = blockIdx.y * PWO;

  for (int idx = tid; idx < PWI * (PWC / 4); idx += 256) {
    int il = idx / (PWC / 4);
    int c4 = idx - il * (PWC / 4);
    float4 v = *(const float4*)(W + ((size_t)(i0 + il) * OUTD_ + o0) * ND + c4 * 4);
    *(float4*)&tile[il * PWP + c4 * 4] = v;
  }
  __syncthreads();

  if (tid < PWC) {
    #pragma unroll
    for (int j = 0; j < PWI / 8; ++j) {
      u16x8 pk;
      #pragma unroll
      for (int jj = 0; jj < 8; ++jj)
        pk[jj] = f2bf(tile[(j * 8 + jj) * PWP + tid]);
      *reinterpret_cast<u16x8*>(&out_ls[tid * OLS + j * 8]) = pk;
    }
  }
  __syncthreads();

  for (int g = tid; g < PWC * (PWI / 8); g += 256) {
    int c  = g >> 2;
    int ig = g & 3;
    int d  = c % 25;
    int o_l = c / 25;
    u16x8 v = *reinterpret_cast<const u16x8*>(&out_ls[c * OLS + ig * 8]);
    size_t rowb = (size_t)(o0 + o_l) * KT2 + (size_t)d * IND_ + i0;
    *reinterpret_cast<u16x8*>(Wt + rowb + ig * 8) = v;
  }
}

// ---------------------------------------------------------------------------
// prep_tail: Wt[o][12800+t] = t<25 ? bf16(bias[o][t]) : 0   (bias K-tail)
// ---------------------------------------------------------------------------
__global__ __launch_bounds__(256) void prep_tail_kernel(
    const float* __restrict__ bias, unsigned short* __restrict__ Wt)
{
  const int idx = blockIdx.x * 256 + threadIdx.x;   // < 512*64
  const int o = idx >> 6;
  const int t = idx & 63;
  unsigned short v = (t < ND) ? f2bf(bias[o * ND + t]) : (unsigned short)0;
  Wt[(size_t)o * KT2 + KTOT + t] = v;
}

// ---------------------------------------------------------------------------
// gemm_fused2: C[o][b] = sum_k A[o][k] * B[b][k] over K=12864 where
//   A[o][k<12800] = Wt, A[o][12800+d] = bias[o][d]
//   B[b][k]       = kb[b,d(k)]*xf[b,i(k)],   B[b][12800+d] = kb[b,d]
// Split-K 4 (last split takes the bias tile).  ONE barrier per K-iter, with
// an EXPLICIT vmcnt/lgkmcnt drain before it (cross-wave LDS-DMA visibility).
// __launch_bounds__(256,2) REQUIRED (round 6: omitting it -> 64 VGPR budget
// -> scratch spills).  LDS 64KB (2 blocks/CU).  Swizzle: conflict-free (R3).
// ---------------------------------------------------------------------------
__global__ __launch_bounds__(256, 2) void gemm_fused2_kernel(
    const unsigned short* __restrict__ Wt, const unsigned short* __restrict__ XFb,
    const float* __restrict__ kb, float* __restrict__ P)
{
  __shared__ unsigned short Als[2][BM * BK];   // 2 x 16 KB
  __shared__ unsigned short Bls[2][BN * BK];   // 2 x 16 KB

  const int tid  = threadIdx.x;
  const int lane = tid & 63;
  const int w    = tid >> 6;
  const int l15  = lane & 15;
  const int quad = lane >> 4;

  // round-3 proven XCD mapping: 512 blocks, id%8 = XCD
  const int id  = blockIdx.x;
  const int xcd = id & 7;
  const int j   = id >> 3;              // [0,64)
  const int bx  = j & 3;                // o-tile
  const int pg  = xcd * 16 + (j >> 2);  // [0,128): (b-tile, split)
  const int by  = pg & 31;
  const int bz  = pg >> 5;              // split [0,4)

  const int o0 = bx * BM;
  const int b0 = by * BN;
  const int ks_begin = bz * 3200;
  const int ks_end   = (bz == 3) ? KT2 : ks_begin + 3200;

  const int o_off = (w & 1) * 64;
  const int b_off = (w >> 1) * 64;
  const int srow  = lane >> 3;                 // 0..7 row-in-chunk
  const int sg    = lane & 7;                  // logical granule
  const int pgr   = sg ^ srow;                 // phys (swizzled) granule
  const int scol  = pgr * 8;                   // A: swizzled SOURCE col
  const int r7    = l15 & 7;

  f32x4 acc[4][4];
  #pragma unroll
  for (int i = 0; i < 4; ++i)
    #pragma unroll
    for (int jj = 0; jj < 4; ++jj) acc[i][jj] = (f32x4)0.0f;

  u16x8 vr[4];
  float sc[4];

  auto issueA = [&](int k0, int buf) {
    #pragma unroll
    for (int c = 0; c < 4; ++c) {
      int chunk = w * 4 + c;
      int r = chunk * 8 + srow;
      gload_lds16(Wt + (size_t)(o0 + r) * KT2 + k0 + scol, &Als[buf][chunk * 512]);
    }
  };
  auto loadB = [&](int k0) {
    if (k0 < KTOT) {
      const int d  = k0 >> 9;
      const int i0 = k0 & 511;
      #pragma unroll
      for (int c = 0; c < 4; ++c) {
        int chunk = w * 4 + c;
        int row = chunk * 8 + srow;
        vr[c] = *(const u16x8*)(XFb + (size_t)(b0 + row) * IND_ + i0 + sg * 8);
        sc[c] = kb[(size_t)(b0 + row) * ND + d];
      }
    } else {
      #pragma unroll
      for (int c = 0; c < 4; ++c) {
        int chunk = w * 4 + c;
        int row = chunk * 8 + srow;
        u16x8 t;
        #pragma unroll
        for (int jj = 0; jj < 8; ++jj) {
          int dd = sg * 8 + jj;
          t[jj] = (dd < ND) ? f2bf(kb[(size_t)(b0 + row) * ND + dd]) : (unsigned short)0;
        }
        vr[c] = t;
        sc[c] = 1.0f;
      }
    }
  };
  auto writeB = [&](int buf) {
    #pragma unroll
    for (int c = 0; c < 4; ++c) {
      int chunk = w * 4 + c;
      int row = chunk * 8 + srow;
      u32x4 rp;
      #pragma unroll
      for (int p4 = 0; p4 < 4; ++p4)
        rp[p4] = pk_bf16(bf2f(vr[c][2 * p4]) * sc[c], bf2f(vr[c][2 * p4 + 1]) * sc[c]);
      *reinterpret_cast<u32x4*>(&Bls[buf][row * BK + pgr * 8]) = rp;
    }
  };

  // prologue: stage iter 0
  issueA(ks_begin, 0);
  loadB(ks_begin);
  writeB(0);
  drain_all();
  __syncthreads();

  // main loop: one barrier per iter, explicit drain before it
  int n = 0;
  for (int k0 = ks_begin; k0 < ks_end; k0 += BK, ++n) {
    const int p = n & 1;
    const int q = p ^ 1;
    const int k1 = k0 + BK;
    const bool more = (k1 < ks_end);

    if (more) {
      issueA(k1, q);      // async -> Als[q]; overlaps MFMA below
      loadB(k1);          // global -> regs; overlaps MFMA below
    }

    #pragma unroll
    for (int ks = 0; ks < 2; ++ks) {
      bf16x8 af[4], bfr[4];
      #pragma unroll
      for (int mf = 0; mf < 4; ++mf) {
        int row = o_off + mf * 16 + l15;
        int g   = (ks * 4 + quad) ^ r7;
        af[mf] = *reinterpret_cast<const bf16x8*>(&Als[p][row * BK + g * 8]);
      }
      #pragma unroll
      for (int nf = 0; nf < 4; ++nf) {
        int row = b_off + nf * 16 + l15;
        int g   = (ks * 4 + quad) ^ r7;
        bfr[nf] = *reinterpret_cast<const bf16x8*>(&Bls[p][row * BK + g * 8]);
      }
      #pragma unroll
      for (int mf = 0; mf < 4; ++mf)
        #pragma unroll
        for (int nf = 0; nf < 4; ++nf)
          acc[mf][nf] = __builtin_amdgcn_mfma_f32_16x16x32_bf16(
              af[mf], bfr[nf], acc[mf][nf], 0, 0, 0);
    }

    if (more) writeB(q);
    drain_all();          // drain own LDS-DMA + ds_writes BEFORE the barrier
    __syncthreads();
  }

  float* Pz = P + (size_t)bz * NB * OUTD_;
  #pragma unroll
  for (int mf = 0; mf < 4; ++mf)
    #pragma unroll
    for (int nf = 0; nf < 4; ++nf) {
      int bg = b0 + b_off + nf * 16 + l15;
      int og = o0 + o_off + mf * 16 + quad * 4;
      *reinterpret_cast<f32x4*>(&Pz[(size_t)bg * OUTD_ + og]) = acc[mf][nf];
    }
}

// ---------------------------------------------------------------------------
// epilogue: out[b][2+o] = relu(P0+P1+P2+P3)   (bias already in GEMM K-tail)
// ---------------------------------------------------------------------------
__global__ __launch_bounds__(256) void epilogue_kernel(
    const float* __restrict__ P, float* __restrict__ out)
{
  const int idx = blockIdx.x * 256 + threadIdx.x;   // < 4096*512
  const int b = idx >> 9;
  const int o = idx & 511;
  const size_t stride = (size_t)NB * OUTD_;
  float s = P[idx] + P[stride + idx] + P[2 * stride + idx] + P[3 * stride + idx];
  out[(size_t)b * XCOLS + 2 + o] = s > 0.0f ? s : 0.0f;
}

// ---------------------------------------------------------------------------
extern "C" void kernel_launch(void* const* d_in, const int* in_sizes, int n_in,
                              void* d_out, int out_size, void* d_ws, size_t ws_size,
                              hipStream_t stream) {
  const float* x    = (const float*)d_in[0];   // 4096 x 514
  const float* W    = (const float*)d_in[1];   // 512 x 512 x 25
  const float* bias = (const float*)d_in[2];   // 512 x 25
  float* out = (float*)d_out;
  char* ws = (char*)d_ws;

  // ws layout (bytes):
  //   XFb 4,194,304 | Wt 512*12864*2 = 13,172,736 | kb 409,600 | P 33,554,432
  const size_t xfb_off = 0;
  const size_t wt_off  = 4194304;
  const size_t kb_off  = wt_off + (size_t)OUTD_ * KT2 * 2;   // 17,367,040
  const size_t p_off   = kb_off + 409600;                     // 17,776,640
  unsigned short* XFb = (unsigned short*)(ws + xfb_off);
  unsigned short* Wt  = (unsigned short*)(ws + wt_off);
  float* kb           = (float*)(ws + kb_off);
  float* P            = (float*)(ws + p_off);

  prep_x_kernel<<<NB / 4, 256, 0, stream>>>(x, XFb, kb, out);
  prep_w_kernel<<<dim3(IND_ / PWI, OUTD_ / PWO), 256, 0, stream>>>(W, Wt);
  prep_tail_kernel<<<(OUTD_ * 64) / 256, 256, 0, stream>>>(bias, Wt);
  gemm_fused2_kernel<<<512, 256, 0, stream>>>(Wt, XFb, kb, P);
  epilogue_kernel<<<(NB * OUTD_) / 256, 256, 0, stream>>>(P, out);
}